// Round 21
// baseline (183.649 us; speedup 1.0000x reference)
//
#include <hip/hip_runtime.h>
#include <hip/hip_bf16.h>
#include <math.h>

#define D 128
#define DH 64
#define CHUNK 2048   // must stay 2048: fill/rowgather use (idx >> 11)
#define EPB 8
#define DEG_EPT 16   // edges per thread in degree section; block covers 4096 edges
#define NREP 8       // XCD-local histogram replicas
typedef __attribute__((ext_vector_type(8))) short bf16x8;
typedef __attribute__((ext_vector_type(4))) float f32x4;
constexpr float KREL = 3.141592653589793f / 1.5f;  // rel * (PI/1.5)

static __device__ __forceinline__ unsigned short bf16u(float f) {
    return __builtin_bit_cast(unsigned short, __float2bfloat16(f));
}
static __device__ __forceinline__ unsigned packbf(float re, float im) {
    return (unsigned)bf16u(re) | ((unsigned)bf16u(im) << 16);
}

// ---- fused prelude: degree+rank (XCD-replicated) | xpack | tables | wswz | relout ----
__global__ __launch_bounds__(256) void k_prelude(
    const float* __restrict__ x, const int* __restrict__ ei,
    const float* __restrict__ rel_embed, const float* __restrict__ loop_rel,
    const float* __restrict__ w_in, const float* __restrict__ w_out,
    const float* __restrict__ w_loop, const float* __restrict__ w_rel,
    int num_rel, int num_ent, int E2,
    int o1, int o2, int o3, int o4,
    unsigned* __restrict__ pt2, unsigned short* __restrict__ Bsw,
    float* __restrict__ out2, unsigned* __restrict__ xp,
    unsigned* __restrict__ degR, unsigned* __restrict__ rnk) {
    int b = blockIdx.x, tid = threadIdx.x;
    int n2 = 2 * num_ent;
    if (b < o1) {
        // degree histogram into replica (b&7): with round-robin block->XCD
        // dispatch, each replica's lines are touched by ONE XCD only.
        unsigned* degrep = degR + (size_t)(b & (NREP - 1)) * n2;
        int base_e = b * (256 * DEG_EPT) + tid;
        int idxv[DEG_EPT]; unsigned rv[DEG_EPT]; bool ok[DEG_EPT];
#pragma unroll
        for (int q = 0; q < DEG_EPT; ++q) {
            int e = base_e + q * 256;
            ok[q] = (e < E2);
            int row = ok[q] ? ei[e] : 0;
            int h = (e < (E2 >> 1)) ? 0 : 1;
            idxv[q] = h * num_ent + row;
        }
#pragma unroll
        for (int q = 0; q < DEG_EPT; ++q)
            if (ok[q]) rv[q] = atomicAdd(&degrep[idxv[q]], 1u);
#pragma unroll
        for (int q = 0; q < DEG_EPT; ++q) {
            int e = base_e + q * 256;
            if (ok[q]) rnk[e] = rv[q];
        }
    } else if (b < o2) {
        // pack x into interleaved bf16
        int i = (b - o1) * 256 + tid;
        if (i >= num_ent * 16) return;
        int row = i >> 4, q = i & 15;
        const float* xr = x + (size_t)row * D + q * 4;
        float4 re4 = *reinterpret_cast<const float4*>(xr);
        float4 im4 = *reinterpret_cast<const float4*>(xr + DH);
        uint4 o;
        o.x = packbf(re4.x, im4.x);
        o.y = packbf(re4.y, im4.y);
        o.z = packbf(re4.z, im4.z);
        o.w = packbf(re4.w, im4.w);
        reinterpret_cast<uint4*>(xp + (size_t)row * 64)[q] = o;
    } else if (b < o3) {
        // packed bf16 cos/sin table: pt2[r*64+c] = {bf16 cos | bf16 sin << 16}
        int i = (b - o2) * 256 + tid;
        int total = (num_rel + 1) * DH;
        if (i >= total) return;
        int r = i / DH, c = i % DH;
        float v = (r < num_rel) ? rel_embed[r * DH + c] : loop_rel[c];
        float ang = v * KREL;
        pt2[i] = packbf(cosf(ang), sinf(ang));
    } else if (b < o4) {
        // weights -> MFMA B-fragment order, k-permuted to interleaved A layout;
        // plane 2 = R @ w_loop (rotation folded inline); all scaled by 1/3.
        int i = (b - o3) * 256 + tid;
        int j = i & 7;
        int lane = (i >> 3) & 63;
        int fid = i >> 9;
        int ct = fid & 7;
        int kt = (fid >> 3) & 3;
        int plane = fid >> 5;
        int kp = kt * 32 + ((lane >> 4) << 3) + j;
        int orig = (kp >> 1) + (kp & 1) * DH;       // bijective perm
        int col = ct * 16 + (lane & 15);
        float val;
        if (plane == 0) val = w_in[orig * 128 + col];
        else if (plane == 1) val = w_out[orig * 128 + col];
        else {
            int kk = orig & (DH - 1);
            float ang = loop_rel[kk] * KREL;
            float c = cosf(ang), s = sinf(ang);
            float w0 = w_loop[kk * 128 + col], w1 = w_loop[(DH + kk) * 128 + col];
            val = (orig < DH) ? fmaf(c, w0, s * w1) : (s * w0 - c * w1);
        }
        Bsw[i] = bf16u(val * (1.0f / 3.0f));
    } else {
        // rel_out = rel_embed @ w_rel
        int i = (b - o4) * 256 + tid;
        if (i >= num_rel * DH) return;
        int r = i / DH, j = i % DH;
        const float* a = rel_embed + r * DH;
        float acc = 0.f;
#pragma unroll 8
        for (int k = 0; k < DH; ++k) acc = fmaf(a[k], w_rel[k * DH + j], acc);
        out2[i] = acc;
    }
}

// ---- combine replicas: degR[r][idx] <- exclusive prefix; deg[idx] = total ----
__global__ void k_scanR(unsigned* __restrict__ degR, unsigned* __restrict__ deg,
                        int n2) {
    int idx = blockIdx.x * blockDim.x + threadIdx.x;
    if (idx >= n2) return;
    unsigned run = 0;
#pragma unroll
    for (int r = 0; r < NREP; ++r) {
        unsigned v = degR[(size_t)r * n2 + idx];
        degR[(size_t)r * n2 + idx] = run;
        run += v;
    }
    deg[idx] = run;
}

// ---- hierarchical exclusive scan over 2N degrees -> rp (chunk-local) ----
__global__ void k_scan1(const unsigned* __restrict__ deg, int n,
                        unsigned* __restrict__ rp, unsigned* __restrict__ partials) {
    __shared__ unsigned s[256];
    int tid = threadIdx.x;
    int base = blockIdx.x * CHUNK + tid * 8;
    unsigned v[8]; unsigned sum = 0;
#pragma unroll
    for (int i = 0; i < 8; ++i) { int g = base + i; v[i] = (g < n) ? deg[g] : 0u; sum += v[i]; }
    s[tid] = sum; __syncthreads();
    for (int off = 1; off < 256; off <<= 1) {
        unsigned t = (tid >= off) ? s[tid - off] : 0u;
        __syncthreads();
        s[tid] += t;
        __syncthreads();
    }
    if (tid == 255) partials[blockIdx.x] = s[255];
    unsigned run = (tid ? s[tid - 1] : 0u);
#pragma unroll
    for (int i = 0; i < 8; ++i) { int g = base + i; if (g < n) rp[g] = run; run += v[i]; }
}

__global__ void k_scan2(unsigned* __restrict__ partials, int nb) {
    __shared__ unsigned s[256];
    int tid = threadIdx.x;
    unsigned v = (tid < nb) ? partials[tid] : 0u;
    s[tid] = v; __syncthreads();
    for (int off = 1; off < 256; off <<= 1) {
        unsigned t = (tid >= off) ? s[tid - off] : 0u;
        __syncthreads();
        s[tid] += t;
        __syncthreads();
    }
    if (tid < nb) partials[tid] = (tid ? s[tid - 1] : 0u);
}

// ---- scatter edges into CSR slots — ATOMIC-FREE
// slot = rp[idx] + partials[idx>>11] + degR_offset[rep(e)][idx] + rnk[e]
__global__ void k_fill(const int* __restrict__ ei, const int* __restrict__ et,
                       int E2, int num_ent,
                       const unsigned* __restrict__ deg, const unsigned* __restrict__ rp,
                       const unsigned* __restrict__ partials,
                       const unsigned* __restrict__ degR,
                       const unsigned* __restrict__ rnk, int2* __restrict__ csr) {
    int e = blockIdx.x * blockDim.x + threadIdx.x;
    if (e >= E2) return;
    int n2 = 2 * num_ent;
    int Eh = E2 >> 1;
    int h = (e < Eh) ? 0 : 1;
    int row = ei[e], col = ei[E2 + e], t = et[e];
    int idx = h * num_ent + row;
    unsigned dr = deg[idx], dc = deg[h * num_ent + col];
    float nrm = (dr > 0u && dc > 0u) ? rsqrtf((float)dr * (float)dc) : 0.f;
    int rep = (e >> 12) & (NREP - 1);   // degree block covers 4096 aligned edges
    unsigned slot = rp[idx] + partials[idx >> 11]
                  + degR[(size_t)rep * n2 + idx] + rnk[e];
    unsigned meta = (unsigned)col | ((unsigned)t << 17) | ((unsigned)(idx & 15) << 26);
    csr[slot] = make_int2((int)meta, __float_as_int(nrm));
}

// ---- row-ownership gather: lane-cooperative csr load + scalar metadata ----
__global__ __launch_bounds__(256) void k_rowgather(
    const unsigned* __restrict__ xp, const int2* __restrict__ csr,
    const unsigned* __restrict__ rp, const unsigned* __restrict__ partials,
    const unsigned* __restrict__ deg, int E2, int n2,
    const unsigned* __restrict__ pt2, unsigned short* __restrict__ T2) {
    int gwave = (int)((blockIdx.x * 256u + threadIdx.x) >> 6);
    int lane = threadIdx.x & 63;
    int vr0 = gwave * 16;
    if (vr0 >= n2) return;
    int vlim = min(vr0 + 16, n2);
    int nrows = vlim - vr0;

    // ---- zero rows with no edges ----
    unsigned dv = (lane < nrows) ? deg[vr0 + lane] : 1u;
    unsigned long long zm = __ballot(lane < nrows && dv == 0u);
    while (zm) {
        int r = (int)(__ffsll((long long)zm) - 1);
        zm &= zm - 1;
        ((unsigned*)(T2 + (size_t)(vr0 + r) * D))[lane] = 0u;
    }

    unsigned beg = rp[vr0] + partials[vr0 >> 11];
    unsigned end = (vlim == n2) ? (unsigned)E2
                                : rp[vlim] + partials[vlim >> 11];
    if (beg >= end) return;

    const unsigned* xpl = xp + lane;
    const unsigned* ptl = pt2 + lane;

    int cur = -1;
    float a_re = 0.f, a_im = 0.f;

    // lane-cooperative batch load: lane (k&7) holds edge s+k's payload
    auto loadbatch = [&](unsigned s) -> int2 {
        unsigned idx = s + (unsigned)(lane & 7);
        if (idx >= end) idx = end - 1;
        return csr[idx];
    };

    int2 mv = loadbatch(beg);
    for (unsigned s = beg; s < end; s += EPB) {
        int2 mvn = mv;
        if (s + EPB < end) mvn = loadbatch(s + EPB);  // prefetch next batch
        int n = (int)min((unsigned)EPB, end - s);

        unsigned meta[EPB]; float nm[EPB];
        unsigned u[EPB], cu[EPB];
#pragma unroll
        for (int k = 0; k < EPB; ++k) {
            meta[k] = (unsigned)__builtin_amdgcn_readlane(mv.x, k);
            unsigned nrw = (unsigned)__builtin_amdgcn_readlane(mv.y, k);
            nm[k] = (k < n) ? __uint_as_float(nrw) : 0.f;
            u[k]  = xpl[(size_t)(meta[k] & 0x1FFFFu) * 64];
            cu[k] = ptl[(size_t)((meta[k] >> 17) & 0x1FFu) * 64];
        }
#pragma unroll
        for (int k = 0; k < EPB; ++k) {
            int lrow = (int)(meta[k] >> 26);
            if (lrow != cur) {  // wave-uniform (scalar branch)
                if (cur >= 0)
                    ((unsigned*)(T2 + (size_t)(vr0 + cur) * D))[lane] = packbf(a_re, a_im);
                cur = lrow; a_re = a_im = 0.f;
            }
            float re = __uint_as_float(u[k] << 16);
            float im = __uint_as_float(u[k] & 0xFFFF0000u);
            float c  = __uint_as_float(cu[k] << 16);
            float sn = __uint_as_float(cu[k] & 0xFFFF0000u);
            float tre = fmaf(re, c, im * sn);
            float tim = fmaf(re, sn, -(im * c));
            a_re = fmaf(nm[k], tre, a_re);
            a_im = fmaf(nm[k], tim, a_im);
        }
        mv = mvn;
    }
    if (cur >= 0)
        ((unsigned*)(T2 + (size_t)(vr0 + cur) * D))[lane] = packbf(a_re, a_im);
}

// ---- MFMA combine: all 3 planes' A-fragments load directly as bf16x8 ----
// (1/3 pre-folded into Bsw)
__global__ __launch_bounds__(256) void k_combine(
    const unsigned short* __restrict__ T2, const unsigned short* __restrict__ XP,
    const unsigned short* __restrict__ Bsw,
    int num_ent, float* __restrict__ out) {
    int tid = threadIdx.x;
    int lane = tid & 63;
    int wid = tid >> 6;
    int base = blockIdx.x * 64 + wid * 16;
    int arow = base + (lane & 15);
    if (arow >= num_ent) arow = num_ent - 1;
    int khi = (lane >> 4) << 3;  // 0,8,16,24

    f32x4 acc[8];
    f32x4 zero = {0.f, 0.f, 0.f, 0.f};
#pragma unroll
    for (int i = 0; i < 8; ++i) acc[i] = zero;

    auto run_kt = [&](bf16x8 afrag, int fid_base) {
#pragma unroll
        for (int ct = 0; ct < 8; ++ct) {
            const unsigned short* bp = Bsw + (((size_t)fid_base * 8 + ct) << 9) + (lane << 3);
            bf16x8 bfrag = *reinterpret_cast<const bf16x8*>(bp);
            acc[ct] = __builtin_amdgcn_mfma_f32_16x16x32_bf16(afrag, bfrag, acc[ct], 0, 0, 0);
        }
    };

    // planes 0,1: T2 (interleaved bf16, A-ready)
#pragma unroll
    for (int plane = 0; plane < 2; ++plane) {
        const unsigned short* Ab = T2 + ((size_t)plane * num_ent + arow) * D;
#pragma unroll
        for (int kt = 0; kt < 4; ++kt) {
            bf16x8 afrag = *reinterpret_cast<const bf16x8*>(Ab + kt * 32 + khi);
            run_kt(afrag, plane * 4 + kt);
        }
    }
    // plane 2: packed x directly (rotation folded into Bsw plane 2)
    {
        const unsigned short* Xb = XP + (size_t)arow * D;
#pragma unroll
        for (int kt = 0; kt < 4; ++kt) {
            bf16x8 afrag = *reinterpret_cast<const bf16x8*>(Xb + kt * 32 + khi);
            run_kt(afrag, 8 + kt);
        }
    }
    // store: C/D layout col=lane&15, row=(lane>>4)*4+reg
    int rbase = base + ((lane >> 4) << 2);
    int colb = lane & 15;
#pragma unroll
    for (int ct = 0; ct < 8; ++ct) {
#pragma unroll
        for (int jj = 0; jj < 4; ++jj) {
            int g = rbase + jj;
            if (g < num_ent) out[(size_t)g * D + ct * 16 + colb] = acc[ct][jj];
        }
    }
}

extern "C" void kernel_launch(void* const* d_in, const int* in_sizes, int n_in,
                              void* d_out, int out_size, void* d_ws, size_t ws_size,
                              hipStream_t stream) {
    const float* x         = (const float*)d_in[0];
    const int*   ei        = (const int*)d_in[1];
    const int*   et        = (const int*)d_in[2];
    const float* rel_embed = (const float*)d_in[3];
    const float* w_loop    = (const float*)d_in[4];
    const float* w_in      = (const float*)d_in[5];
    const float* w_out     = (const float*)d_in[6];
    const float* w_rel     = (const float*)d_in[7];
    const float* loop_rel  = (const float*)d_in[8];
    float* out = (float*)d_out;

    int num_ent = in_sizes[0] / D;
    int E2      = in_sizes[2];
    int num_rel = in_sizes[3] / DH;
    float* out2 = out + (size_t)num_ent * D;

    int n2 = 2 * num_ent;
    char* ws = (char*)d_ws;
    unsigned* degR = (unsigned*)ws;                // NREP * 2N (replica histograms -> offsets)
    unsigned* deg  = degR + (size_t)NREP * n2;     // 2N totals
    unsigned* rp   = deg + n2;                     // 2N
    unsigned* partials = rp + n2;                  // 256
    unsigned* rnk = partials + 256;                // E2
    size_t off = ((size_t)(NREP + 2) * n2 + 256 + E2) * sizeof(unsigned);
    off = (off + 15) & ~(size_t)15;
    int2* csr = (int2*)(ws + off);                 // E2 int2 (8 B)
    unsigned* pt2 = (unsigned*)(csr + E2);         // (num_rel+1)*64 dwords
    unsigned short* Bsw = (unsigned short*)(pt2 + (size_t)(num_rel + 1) * DH);  // 49152
    unsigned short* T2 = Bsw + (size_t)3 * 4 * 8 * 512;  // 2N*128 bf16
    unsigned* xp = (unsigned*)(T2 + (size_t)n2 * D);     // N*64 dwords

    hipMemsetAsync(degR, 0, (size_t)NREP * n2 * sizeof(unsigned), stream);

    // fused prelude block ranges: degree | xpack | tables | wswz | relout
    int nb_deg = (E2 + 256 * DEG_EPT - 1) / (256 * DEG_EPT);
    int nb_xpk = (num_ent * 16 + 255) / 256;
    int nb_tab = ((num_rel + 1) * DH + 255) / 256;
    int nb_wsw = (3 * 4 * 8 * 512) / 256;
    int nb_rel = (num_rel * DH + 255) / 256;
    int o1 = nb_deg, o2 = o1 + nb_xpk, o3 = o2 + nb_tab, o4 = o3 + nb_wsw;
    int o5 = o4 + nb_rel;
    k_prelude<<<o5, 256, 0, stream>>>(x, ei, rel_embed, loop_rel,
                                      w_in, w_out, w_loop, w_rel,
                                      num_rel, num_ent, E2, o1, o2, o3, o4,
                                      pt2, Bsw, out2, xp, degR, rnk);

    k_scanR<<<(n2 + 255) / 256, 256, 0, stream>>>(degR, deg, n2);

    int nb1 = (n2 + CHUNK - 1) / CHUNK;
    k_scan1<<<nb1, 256, 0, stream>>>(deg, n2, rp, partials);
    k_scan2<<<1, 256, 0, stream>>>(partials, nb1);

    k_fill<<<(E2 + 255) / 256, 256, 0, stream>>>(ei, et, E2, num_ent, deg, rp,
                                                 partials, degR, rnk, csr);

    int nwaves = (n2 + 15) / 16;
    int gblocks = (nwaves * 64 + 255) / 256;
    k_rowgather<<<gblocks, 256, 0, stream>>>(xp, csr, rp, partials, deg,
                                             E2, n2, pt2, T2);

    int cb = (num_ent + 63) / 64;
    k_combine<<<cb, 256, 0, stream>>>(T2, (const unsigned short*)xp, Bsw, num_ent, out);
}

// Round 22
// 175.935 us; speedup vs baseline: 1.0438x; 1.0438x over previous
//
#include <hip/hip_runtime.h>
#include <hip/hip_bf16.h>
#include <math.h>

#define D 128
#define DH 64
#define CHUNK 2048   // must stay 2048: fill/rowgather use (idx >> 11)
#define EPB 8
#define DEG_EPT 16   // edges per thread in the degree section (atomic ILP)
typedef __attribute__((ext_vector_type(8))) short bf16x8;
typedef __attribute__((ext_vector_type(4))) float f32x4;
constexpr float KREL = 3.141592653589793f / 1.5f;  // rel * (PI/1.5)

static __device__ __forceinline__ unsigned short bf16u(float f) {
    return __builtin_bit_cast(unsigned short, __float2bfloat16(f));
}
static __device__ __forceinline__ unsigned packbf(float re, float im) {
    return (unsigned)bf16u(re) | ((unsigned)bf16u(im) << 16);
}

// ---- fused prelude: degree+rank+meta | xpack | tables | wswz | relout ----
// degree first (lowest block ids); DEG_EPT edges/thread for atomic ILP.
// Emits em[e] = col|typ<<17|lrow<<26 and e2[e] = idx|rnk<<18 so k_fill
// never touches ei/et again.
__global__ __launch_bounds__(256) void k_prelude(
    const float* __restrict__ x, const int* __restrict__ ei,
    const int* __restrict__ et,
    const float* __restrict__ rel_embed, const float* __restrict__ loop_rel,
    const float* __restrict__ w_in, const float* __restrict__ w_out,
    const float* __restrict__ w_loop, const float* __restrict__ w_rel,
    int num_rel, int num_ent, int E2,
    int o1, int o2, int o3, int o4,
    unsigned* __restrict__ pt2, unsigned short* __restrict__ Bsw,
    float* __restrict__ out2, unsigned* __restrict__ xp,
    unsigned* __restrict__ deg,
    unsigned* __restrict__ em, unsigned* __restrict__ e2) {
    int b = blockIdx.x, tid = threadIdx.x;
    if (b < o1) {
        int base_e = b * (256 * DEG_EPT) + tid;
        int idxv[DEG_EPT]; unsigned rv[DEG_EPT]; bool ok[DEG_EPT];
        unsigned mw[DEG_EPT];
#pragma unroll
        for (int q = 0; q < DEG_EPT; ++q) {
            int e = base_e + q * 256;
            ok[q] = (e < E2);
            int ec = ok[q] ? e : 0;
            int row = ei[ec];
            int col = ei[E2 + ec];
            int t   = et[ec];
            int h = (e < (E2 >> 1)) ? 0 : 1;
            idxv[q] = h * num_ent + row;
            mw[q] = (unsigned)col | ((unsigned)t << 17)
                  | ((unsigned)(idxv[q] & 15) << 26);
        }
#pragma unroll
        for (int q = 0; q < DEG_EPT; ++q)
            if (ok[q]) rv[q] = atomicAdd(&deg[idxv[q]], 1u);
#pragma unroll
        for (int q = 0; q < DEG_EPT; ++q) {
            int e = base_e + q * 256;
            if (ok[q]) {
                em[e] = mw[q];
                e2[e] = (unsigned)idxv[q] | (rv[q] << 18);  // rnk << 18 (deg ≪ 16k)
            }
        }
    } else if (b < o2) {
        // pack x into interleaved bf16
        int i = (b - o1) * 256 + tid;
        if (i >= num_ent * 16) return;
        int row = i >> 4, q = i & 15;
        const float* xr = x + (size_t)row * D + q * 4;
        float4 re4 = *reinterpret_cast<const float4*>(xr);
        float4 im4 = *reinterpret_cast<const float4*>(xr + DH);
        uint4 o;
        o.x = packbf(re4.x, im4.x);
        o.y = packbf(re4.y, im4.y);
        o.z = packbf(re4.z, im4.z);
        o.w = packbf(re4.w, im4.w);
        reinterpret_cast<uint4*>(xp + (size_t)row * 64)[q] = o;
    } else if (b < o3) {
        // packed bf16 cos/sin table: pt2[r*64+c] = {bf16 cos | bf16 sin << 16}
        int i = (b - o2) * 256 + tid;
        int total = (num_rel + 1) * DH;
        if (i >= total) return;
        int r = i / DH, c = i % DH;
        float v = (r < num_rel) ? rel_embed[r * DH + c] : loop_rel[c];
        float ang = v * KREL;
        pt2[i] = packbf(cosf(ang), sinf(ang));
    } else if (b < o4) {
        // weights -> MFMA B-fragment order, k-permuted to interleaved A layout;
        // plane 2 = R @ w_loop (rotation folded inline); all scaled by 1/3.
        int i = (b - o3) * 256 + tid;
        int j = i & 7;
        int lane = (i >> 3) & 63;
        int fid = i >> 9;
        int ct = fid & 7;
        int kt = (fid >> 3) & 3;
        int plane = fid >> 5;
        int kp = kt * 32 + ((lane >> 4) << 3) + j;
        int orig = (kp >> 1) + (kp & 1) * DH;       // bijective perm
        int col = ct * 16 + (lane & 15);
        float val;
        if (plane == 0) val = w_in[orig * 128 + col];
        else if (plane == 1) val = w_out[orig * 128 + col];
        else {
            int kk = orig & (DH - 1);
            float ang = loop_rel[kk] * KREL;
            float c = cosf(ang), s = sinf(ang);
            float w0 = w_loop[kk * 128 + col], w1 = w_loop[(DH + kk) * 128 + col];
            val = (orig < DH) ? fmaf(c, w0, s * w1) : (s * w0 - c * w1);
        }
        Bsw[i] = bf16u(val * (1.0f / 3.0f));
    } else {
        // rel_out = rel_embed @ w_rel
        int i = (b - o4) * 256 + tid;
        if (i >= num_rel * DH) return;
        int r = i / DH, j = i % DH;
        const float* a = rel_embed + r * DH;
        float acc = 0.f;
#pragma unroll 8
        for (int k = 0; k < DH; ++k) acc = fmaf(a[k], w_rel[k * DH + j], acc);
        out2[i] = acc;
    }
}

// ---- hierarchical exclusive scan over 2N degrees -> rp (chunk-local) ----
__global__ void k_scan1(const unsigned* __restrict__ deg, int n,
                        unsigned* __restrict__ rp, unsigned* __restrict__ partials) {
    __shared__ unsigned s[256];
    int tid = threadIdx.x;
    int base = blockIdx.x * CHUNK + tid * 8;
    unsigned v[8]; unsigned sum = 0;
#pragma unroll
    for (int i = 0; i < 8; ++i) { int g = base + i; v[i] = (g < n) ? deg[g] : 0u; sum += v[i]; }
    s[tid] = sum; __syncthreads();
    for (int off = 1; off < 256; off <<= 1) {
        unsigned t = (tid >= off) ? s[tid - off] : 0u;
        __syncthreads();
        s[tid] += t;
        __syncthreads();
    }
    if (tid == 255) partials[blockIdx.x] = s[255];
    unsigned run = (tid ? s[tid - 1] : 0u);
#pragma unroll
    for (int i = 0; i < 8; ++i) { int g = base + i; if (g < n) rp[g] = run; run += v[i]; }
}

__global__ void k_scan2(unsigned* __restrict__ partials, int nb) {
    __shared__ unsigned s[256];
    int tid = threadIdx.x;
    unsigned v = (tid < nb) ? partials[tid] : 0u;
    s[tid] = v; __syncthreads();
    for (int off = 1; off < 256; off <<= 1) {
        unsigned t = (tid >= off) ? s[tid - off] : 0u;
        __syncthreads();
        s[tid] += t;
        __syncthreads();
    }
    if (tid < nb) partials[tid] = (tid ? s[tid - 1] : 0u);
}

// ---- scatter edges into CSR slots — ATOMIC-FREE, ei/et-free
// slot = rp[idx] + partials[idx>>11] + rnk; all edge data from em/e2.
__global__ void k_fill(int E2, int num_ent,
                       const unsigned* __restrict__ deg, const unsigned* __restrict__ rp,
                       const unsigned* __restrict__ partials,
                       const unsigned* __restrict__ em, const unsigned* __restrict__ e2,
                       int2* __restrict__ csr) {
    int e = blockIdx.x * blockDim.x + threadIdx.x;
    if (e >= E2) return;
    unsigned meta = em[e];
    unsigned w2 = e2[e];
    unsigned idx = w2 & 0x3FFFFu;        // 18-bit idx (2N < 262144)
    unsigned rk = w2 >> 18;
    unsigned col = meta & 0x1FFFFu;
    unsigned colidx = (idx >= (unsigned)num_ent) ? col + (unsigned)num_ent : col;
    unsigned dr = deg[idx], dc = deg[colidx];
    float nrm = (dr > 0u && dc > 0u) ? rsqrtf((float)dr * (float)dc) : 0.f;
    unsigned slot = rp[idx] + partials[idx >> 11] + rk;
    csr[slot] = make_int2((int)meta, __float_as_int(nrm));
}

// ---- row-ownership gather: lane-cooperative csr load + scalar metadata ----
// Applies partials to rp on the fly; zeroes its own empty rows.
__global__ __launch_bounds__(256) void k_rowgather(
    const unsigned* __restrict__ xp, const int2* __restrict__ csr,
    const unsigned* __restrict__ rp, const unsigned* __restrict__ partials,
    const unsigned* __restrict__ deg, int E2, int n2,
    const unsigned* __restrict__ pt2, unsigned short* __restrict__ T2) {
    int gwave = (int)((blockIdx.x * 256u + threadIdx.x) >> 6);
    int lane = threadIdx.x & 63;
    int vr0 = gwave * 16;
    if (vr0 >= n2) return;
    int vlim = min(vr0 + 16, n2);
    int nrows = vlim - vr0;

    // ---- zero rows with no edges ----
    unsigned dv = (lane < nrows) ? deg[vr0 + lane] : 1u;
    unsigned long long zm = __ballot(lane < nrows && dv == 0u);
    while (zm) {
        int r = (int)(__ffsll((long long)zm) - 1);
        zm &= zm - 1;
        ((unsigned*)(T2 + (size_t)(vr0 + r) * D))[lane] = 0u;
    }

    unsigned beg = rp[vr0] + partials[vr0 >> 11];
    unsigned end = (vlim == n2) ? (unsigned)E2
                                : rp[vlim] + partials[vlim >> 11];
    if (beg >= end) return;

    const unsigned* xpl = xp + lane;
    const unsigned* ptl = pt2 + lane;

    int cur = -1;
    float a_re = 0.f, a_im = 0.f;

    // lane-cooperative batch load: lane (k&7) holds edge s+k's payload
    auto loadbatch = [&](unsigned s) -> int2 {
        unsigned idx = s + (unsigned)(lane & 7);
        if (idx >= end) idx = end - 1;
        return csr[idx];
    };

    int2 mv = loadbatch(beg);
    for (unsigned s = beg; s < end; s += EPB) {
        int2 mvn = mv;
        if (s + EPB < end) mvn = loadbatch(s + EPB);  // prefetch next batch
        int n = (int)min((unsigned)EPB, end - s);

        unsigned meta[EPB]; float nm[EPB];
        unsigned u[EPB], cu[EPB];
#pragma unroll
        for (int k = 0; k < EPB; ++k) {
            meta[k] = (unsigned)__builtin_amdgcn_readlane(mv.x, k);
            unsigned nrw = (unsigned)__builtin_amdgcn_readlane(mv.y, k);
            nm[k] = (k < n) ? __uint_as_float(nrw) : 0.f;
            u[k]  = xpl[(size_t)(meta[k] & 0x1FFFFu) * 64];
            cu[k] = ptl[(size_t)((meta[k] >> 17) & 0x1FFu) * 64];
        }
#pragma unroll
        for (int k = 0; k < EPB; ++k) {
            int lrow = (int)(meta[k] >> 26);
            if (lrow != cur) {  // wave-uniform (scalar branch)
                if (cur >= 0)
                    ((unsigned*)(T2 + (size_t)(vr0 + cur) * D))[lane] = packbf(a_re, a_im);
                cur = lrow; a_re = a_im = 0.f;
            }
            float re = __uint_as_float(u[k] << 16);
            float im = __uint_as_float(u[k] & 0xFFFF0000u);
            float c  = __uint_as_float(cu[k] << 16);
            float sn = __uint_as_float(cu[k] & 0xFFFF0000u);
            float tre = fmaf(re, c, im * sn);
            float tim = fmaf(re, sn, -(im * c));
            a_re = fmaf(nm[k], tre, a_re);
            a_im = fmaf(nm[k], tim, a_im);
        }
        mv = mvn;
    }
    if (cur >= 0)
        ((unsigned*)(T2 + (size_t)(vr0 + cur) * D))[lane] = packbf(a_re, a_im);
}

// ---- MFMA combine: all 3 planes' A-fragments load directly as bf16x8 ----
// (1/3 pre-folded into Bsw)
__global__ __launch_bounds__(256) void k_combine(
    const unsigned short* __restrict__ T2, const unsigned short* __restrict__ XP,
    const unsigned short* __restrict__ Bsw,
    int num_ent, float* __restrict__ out) {
    int tid = threadIdx.x;
    int lane = tid & 63;
    int wid = tid >> 6;
    int base = blockIdx.x * 64 + wid * 16;
    int arow = base + (lane & 15);
    if (arow >= num_ent) arow = num_ent - 1;
    int khi = (lane >> 4) << 3;  // 0,8,16,24

    f32x4 acc[8];
    f32x4 zero = {0.f, 0.f, 0.f, 0.f};
#pragma unroll
    for (int i = 0; i < 8; ++i) acc[i] = zero;

    auto run_kt = [&](bf16x8 afrag, int fid_base) {
#pragma unroll
        for (int ct = 0; ct < 8; ++ct) {
            const unsigned short* bp = Bsw + (((size_t)fid_base * 8 + ct) << 9) + (lane << 3);
            bf16x8 bfrag = *reinterpret_cast<const bf16x8*>(bp);
            acc[ct] = __builtin_amdgcn_mfma_f32_16x16x32_bf16(afrag, bfrag, acc[ct], 0, 0, 0);
        }
    };

    // planes 0,1: T2 (interleaved bf16, A-ready)
#pragma unroll
    for (int plane = 0; plane < 2; ++plane) {
        const unsigned short* Ab = T2 + ((size_t)plane * num_ent + arow) * D;
#pragma unroll
        for (int kt = 0; kt < 4; ++kt) {
            bf16x8 afrag = *reinterpret_cast<const bf16x8*>(Ab + kt * 32 + khi);
            run_kt(afrag, plane * 4 + kt);
        }
    }
    // plane 2: packed x directly (rotation folded into Bsw plane 2)
    {
        const unsigned short* Xb = XP + (size_t)arow * D;
#pragma unroll
        for (int kt = 0; kt < 4; ++kt) {
            bf16x8 afrag = *reinterpret_cast<const bf16x8*>(Xb + kt * 32 + khi);
            run_kt(afrag, 8 + kt);
        }
    }
    // store: C/D layout col=lane&15, row=(lane>>4)*4+reg
    int rbase = base + ((lane >> 4) << 2);
    int colb = lane & 15;
#pragma unroll
    for (int ct = 0; ct < 8; ++ct) {
#pragma unroll
        for (int jj = 0; jj < 4; ++jj) {
            int g = rbase + jj;
            if (g < num_ent) out[(size_t)g * D + ct * 16 + colb] = acc[ct][jj];
        }
    }
}

extern "C" void kernel_launch(void* const* d_in, const int* in_sizes, int n_in,
                              void* d_out, int out_size, void* d_ws, size_t ws_size,
                              hipStream_t stream) {
    const float* x         = (const float*)d_in[0];
    const int*   ei        = (const int*)d_in[1];
    const int*   et        = (const int*)d_in[2];
    const float* rel_embed = (const float*)d_in[3];
    const float* w_loop    = (const float*)d_in[4];
    const float* w_in      = (const float*)d_in[5];
    const float* w_out     = (const float*)d_in[6];
    const float* w_rel     = (const float*)d_in[7];
    const float* loop_rel  = (const float*)d_in[8];
    float* out = (float*)d_out;

    int num_ent = in_sizes[0] / D;
    int E2      = in_sizes[2];
    int num_rel = in_sizes[3] / DH;
    float* out2 = out + (size_t)num_ent * D;

    int n2 = 2 * num_ent;
    char* ws = (char*)d_ws;
    unsigned* deg = (unsigned*)ws;                 // 2N
    unsigned* rp  = deg + n2;                      // 2N
    unsigned* partials = rp + n2;                  // 256
    unsigned* em  = partials + 256;                // E2 (meta word)
    unsigned* e2  = em + E2;                       // E2 (idx | rnk<<18)
    size_t off = (size_t)(2 * n2 + 256 + 2 * (size_t)E2) * sizeof(unsigned);
    off = (off + 15) & ~(size_t)15;
    int2* csr = (int2*)(ws + off);                 // E2 int2 (8 B)
    unsigned* pt2 = (unsigned*)(csr + E2);         // (num_rel+1)*64 dwords
    unsigned short* Bsw = (unsigned short*)(pt2 + (size_t)(num_rel + 1) * DH);  // 49152
    unsigned short* T2 = Bsw + (size_t)3 * 4 * 8 * 512;  // 2N*128 bf16
    unsigned* xp = (unsigned*)(T2 + (size_t)n2 * D);     // N*64 dwords

    hipMemsetAsync(deg, 0, (size_t)n2 * sizeof(unsigned), stream);

    // fused prelude block ranges: degree | xpack | tables | wswz | relout
    int nb_deg = (E2 + 256 * DEG_EPT - 1) / (256 * DEG_EPT);
    int nb_xpk = (num_ent * 16 + 255) / 256;
    int nb_tab = ((num_rel + 1) * DH + 255) / 256;
    int nb_wsw = (3 * 4 * 8 * 512) / 256;
    int nb_rel = (num_rel * DH + 255) / 256;
    int o1 = nb_deg, o2 = o1 + nb_xpk, o3 = o2 + nb_tab, o4 = o3 + nb_wsw;
    int o5 = o4 + nb_rel;
    k_prelude<<<o5, 256, 0, stream>>>(x, ei, et, rel_embed, loop_rel,
                                      w_in, w_out, w_loop, w_rel,
                                      num_rel, num_ent, E2, o1, o2, o3, o4,
                                      pt2, Bsw, out2, xp, deg, em, e2);

    int nb1 = (n2 + CHUNK - 1) / CHUNK;
    k_scan1<<<nb1, 256, 0, stream>>>(deg, n2, rp, partials);
    k_scan2<<<1, 256, 0, stream>>>(partials, nb1);

    k_fill<<<(E2 + 255) / 256, 256, 0, stream>>>(E2, num_ent, deg, rp,
                                                 partials, em, e2, csr);

    int nwaves = (n2 + 15) / 16;
    int gblocks = (nwaves * 64 + 255) / 256;
    k_rowgather<<<gblocks, 256, 0, stream>>>(xp, csr, rp, partials, deg,
                                             E2, n2, pt2, T2);

    int cb = (num_ent + 63) / 64;
    k_combine<<<cb, 256, 0, stream>>>(T2, (const unsigned short*)xp, Bsw, num_ent, out);
}

// Round 23
// 169.188 us; speedup vs baseline: 1.0855x; 1.0399x over previous
//
#include <hip/hip_runtime.h>
#include <hip/hip_bf16.h>
#include <math.h>

#define D 128
#define DH 64
#define CHUNK 2048   // must stay 2048: fill/rowgather use (idx >> 11)
#define EPB 8
#define DEG_EPT 16   // edges per thread in the degree section (atomic ILP)
typedef __attribute__((ext_vector_type(8))) short bf16x8;
typedef __attribute__((ext_vector_type(4))) float f32x4;
constexpr float KREL = 3.141592653589793f / 1.5f;  // rel * (PI/1.5)

static __device__ __forceinline__ unsigned short bf16u(float f) {
    return __builtin_bit_cast(unsigned short, __float2bfloat16(f));
}
static __device__ __forceinline__ unsigned packbf(float re, float im) {
    return (unsigned)bf16u(re) | ((unsigned)bf16u(im) << 16);
}

// ---- fused prelude: degree+rank | xpack | tables | wswz | relout ----
// degree first (lowest block ids); DEG_EPT edges/thread for atomic ILP.
__global__ __launch_bounds__(256) void k_prelude(
    const float* __restrict__ x, const int* __restrict__ ei,
    const float* __restrict__ rel_embed, const float* __restrict__ loop_rel,
    const float* __restrict__ w_in, const float* __restrict__ w_out,
    const float* __restrict__ w_loop, const float* __restrict__ w_rel,
    int num_rel, int num_ent, int E2,
    int o1, int o2, int o3, int o4,
    unsigned* __restrict__ pt2, unsigned short* __restrict__ Bsw,
    float* __restrict__ out2, unsigned* __restrict__ xp,
    unsigned* __restrict__ deg, unsigned* __restrict__ rnk) {
    int b = blockIdx.x, tid = threadIdx.x;
    if (b < o1) {
        // degree histogram over 2N virtual rows; rank = within-row order.
        int base_e = b * (256 * DEG_EPT) + tid;
        int idxv[DEG_EPT]; unsigned rv[DEG_EPT]; bool ok[DEG_EPT];
#pragma unroll
        for (int q = 0; q < DEG_EPT; ++q) {
            int e = base_e + q * 256;
            ok[q] = (e < E2);
            int row = ok[q] ? ei[e] : 0;
            int h = (e < (E2 >> 1)) ? 0 : 1;
            idxv[q] = h * num_ent + row;
        }
#pragma unroll
        for (int q = 0; q < DEG_EPT; ++q)
            if (ok[q]) rv[q] = atomicAdd(&deg[idxv[q]], 1u);
#pragma unroll
        for (int q = 0; q < DEG_EPT; ++q) {
            int e = base_e + q * 256;
            if (ok[q]) rnk[e] = rv[q];
        }
    } else if (b < o2) {
        // pack x into interleaved bf16
        int i = (b - o1) * 256 + tid;
        if (i >= num_ent * 16) return;
        int row = i >> 4, q = i & 15;
        const float* xr = x + (size_t)row * D + q * 4;
        float4 re4 = *reinterpret_cast<const float4*>(xr);
        float4 im4 = *reinterpret_cast<const float4*>(xr + DH);
        uint4 o;
        o.x = packbf(re4.x, im4.x);
        o.y = packbf(re4.y, im4.y);
        o.z = packbf(re4.z, im4.z);
        o.w = packbf(re4.w, im4.w);
        reinterpret_cast<uint4*>(xp + (size_t)row * 64)[q] = o;
    } else if (b < o3) {
        // packed bf16 cos/sin table: pt2[r*64+c] = {bf16 cos | bf16 sin << 16}
        int i = (b - o2) * 256 + tid;
        int total = (num_rel + 1) * DH;
        if (i >= total) return;
        int r = i / DH, c = i % DH;
        float v = (r < num_rel) ? rel_embed[r * DH + c] : loop_rel[c];
        float ang = v * KREL;
        pt2[i] = packbf(cosf(ang), sinf(ang));
    } else if (b < o4) {
        // weights -> MFMA B-fragment order, k-permuted to interleaved A layout;
        // plane 2 = R @ w_loop (rotation folded inline); all scaled by 1/3.
        int i = (b - o3) * 256 + tid;
        int j = i & 7;
        int lane = (i >> 3) & 63;
        int fid = i >> 9;
        int ct = fid & 7;
        int kt = (fid >> 3) & 3;
        int plane = fid >> 5;
        int kp = kt * 32 + ((lane >> 4) << 3) + j;
        int orig = (kp >> 1) + (kp & 1) * DH;       // bijective perm
        int col = ct * 16 + (lane & 15);
        float val;
        if (plane == 0) val = w_in[orig * 128 + col];
        else if (plane == 1) val = w_out[orig * 128 + col];
        else {
            int kk = orig & (DH - 1);
            float ang = loop_rel[kk] * KREL;
            float c = cosf(ang), s = sinf(ang);
            float w0 = w_loop[kk * 128 + col], w1 = w_loop[(DH + kk) * 128 + col];
            val = (orig < DH) ? fmaf(c, w0, s * w1) : (s * w0 - c * w1);
        }
        Bsw[i] = bf16u(val * (1.0f / 3.0f));
    } else {
        // rel_out = rel_embed @ w_rel
        int i = (b - o4) * 256 + tid;
        if (i >= num_rel * DH) return;
        int r = i / DH, j = i % DH;
        const float* a = rel_embed + r * DH;
        float acc = 0.f;
#pragma unroll 8
        for (int k = 0; k < DH; ++k) acc = fmaf(a[k], w_rel[k * DH + j], acc);
        out2[i] = acc;
    }
}

// ---- hierarchical exclusive scan over 2N degrees -> rp (chunk-local) ----
__global__ void k_scan1(const unsigned* __restrict__ deg, int n,
                        unsigned* __restrict__ rp, unsigned* __restrict__ partials) {
    __shared__ unsigned s[256];
    int tid = threadIdx.x;
    int base = blockIdx.x * CHUNK + tid * 8;
    unsigned v[8]; unsigned sum = 0;
#pragma unroll
    for (int i = 0; i < 8; ++i) { int g = base + i; v[i] = (g < n) ? deg[g] : 0u; sum += v[i]; }
    s[tid] = sum; __syncthreads();
    for (int off = 1; off < 256; off <<= 1) {
        unsigned t = (tid >= off) ? s[tid - off] : 0u;
        __syncthreads();
        s[tid] += t;
        __syncthreads();
    }
    if (tid == 255) partials[blockIdx.x] = s[255];
    unsigned run = (tid ? s[tid - 1] : 0u);
#pragma unroll
    for (int i = 0; i < 8; ++i) { int g = base + i; if (g < n) rp[g] = run; run += v[i]; }
}

__global__ void k_scan2(unsigned* __restrict__ partials, int nb) {
    __shared__ unsigned s[256];
    int tid = threadIdx.x;
    unsigned v = (tid < nb) ? partials[tid] : 0u;
    s[tid] = v; __syncthreads();
    for (int off = 1; off < 256; off <<= 1) {
        unsigned t = (tid >= off) ? s[tid - off] : 0u;
        __syncthreads();
        s[tid] += t;
        __syncthreads();
    }
    if (tid < nb) partials[tid] = (tid ? s[tid - 1] : 0u);
}

// ---- scatter edges into CSR slots — ATOMIC-FREE, partials applied on the fly
// slot = rp[idx] + partials[idx>>11] + rnk[e]   (no scan3 pass needed)
__global__ void k_fill(const int* __restrict__ ei, const int* __restrict__ et,
                       int E2, int num_ent,
                       const unsigned* __restrict__ deg, const unsigned* __restrict__ rp,
                       const unsigned* __restrict__ partials,
                       const unsigned* __restrict__ rnk, int2* __restrict__ csr) {
    int e = blockIdx.x * blockDim.x + threadIdx.x;
    if (e >= E2) return;
    int Eh = E2 >> 1;
    int h = (e < Eh) ? 0 : 1;
    int row = ei[e], col = ei[E2 + e], t = et[e];
    int idx = h * num_ent + row;
    unsigned dr = deg[idx], dc = deg[h * num_ent + col];
    float nrm = (dr > 0u && dc > 0u) ? rsqrtf((float)dr * (float)dc) : 0.f;
    unsigned slot = rp[idx] + partials[idx >> 11] + rnk[e];
    unsigned meta = (unsigned)col | ((unsigned)t << 17) | ((unsigned)(idx & 15) << 26);
    csr[slot] = make_int2((int)meta, __float_as_int(nrm));
}

// ---- row-ownership gather: lane-cooperative csr load + scalar metadata ----
// Applies partials to rp on the fly; zeroes its own empty rows.
__global__ __launch_bounds__(256) void k_rowgather(
    const unsigned* __restrict__ xp, const int2* __restrict__ csr,
    const unsigned* __restrict__ rp, const unsigned* __restrict__ partials,
    const unsigned* __restrict__ deg, int E2, int n2,
    const unsigned* __restrict__ pt2, unsigned short* __restrict__ T2) {
    int gwave = (int)((blockIdx.x * 256u + threadIdx.x) >> 6);
    int lane = threadIdx.x & 63;
    int vr0 = gwave * 16;
    if (vr0 >= n2) return;
    int vlim = min(vr0 + 16, n2);
    int nrows = vlim - vr0;

    // ---- zero rows with no edges ----
    unsigned dv = (lane < nrows) ? deg[vr0 + lane] : 1u;
    unsigned long long zm = __ballot(lane < nrows && dv == 0u);
    while (zm) {
        int r = (int)(__ffsll((long long)zm) - 1);
        zm &= zm - 1;
        ((unsigned*)(T2 + (size_t)(vr0 + r) * D))[lane] = 0u;
    }

    unsigned beg = rp[vr0] + partials[vr0 >> 11];
    unsigned end = (vlim == n2) ? (unsigned)E2
                                : rp[vlim] + partials[vlim >> 11];
    if (beg >= end) return;

    const unsigned* xpl = xp + lane;
    const unsigned* ptl = pt2 + lane;

    int cur = -1;
    float a_re = 0.f, a_im = 0.f;

    // lane-cooperative batch load: lane (k&7) holds edge s+k's payload
    auto loadbatch = [&](unsigned s) -> int2 {
        unsigned idx = s + (unsigned)(lane & 7);
        if (idx >= end) idx = end - 1;
        return csr[idx];
    };

    int2 mv = loadbatch(beg);
    for (unsigned s = beg; s < end; s += EPB) {
        int2 mvn = mv;
        if (s + EPB < end) mvn = loadbatch(s + EPB);  // prefetch next batch
        int n = (int)min((unsigned)EPB, end - s);

        unsigned meta[EPB]; float nm[EPB];
        unsigned u[EPB], cu[EPB];
#pragma unroll
        for (int k = 0; k < EPB; ++k) {
            meta[k] = (unsigned)__builtin_amdgcn_readlane(mv.x, k);
            unsigned nrw = (unsigned)__builtin_amdgcn_readlane(mv.y, k);
            nm[k] = (k < n) ? __uint_as_float(nrw) : 0.f;
            u[k]  = xpl[(size_t)(meta[k] & 0x1FFFFu) * 64];
            cu[k] = ptl[(size_t)((meta[k] >> 17) & 0x1FFu) * 64];
        }
#pragma unroll
        for (int k = 0; k < EPB; ++k) {
            int lrow = (int)(meta[k] >> 26);
            if (lrow != cur) {  // wave-uniform (scalar branch)
                if (cur >= 0)
                    ((unsigned*)(T2 + (size_t)(vr0 + cur) * D))[lane] = packbf(a_re, a_im);
                cur = lrow; a_re = a_im = 0.f;
            }
            float re = __uint_as_float(u[k] << 16);
            float im = __uint_as_float(u[k] & 0xFFFF0000u);
            float c  = __uint_as_float(cu[k] << 16);
            float sn = __uint_as_float(cu[k] & 0xFFFF0000u);
            float tre = fmaf(re, c, im * sn);
            float tim = fmaf(re, sn, -(im * c));
            a_re = fmaf(nm[k], tre, a_re);
            a_im = fmaf(nm[k], tim, a_im);
        }
        mv = mvn;
    }
    if (cur >= 0)
        ((unsigned*)(T2 + (size_t)(vr0 + cur) * D))[lane] = packbf(a_re, a_im);
}

// ---- MFMA combine: all 3 planes' A-fragments load directly as bf16x8 ----
// (1/3 pre-folded into Bsw)
__global__ __launch_bounds__(256) void k_combine(
    const unsigned short* __restrict__ T2, const unsigned short* __restrict__ XP,
    const unsigned short* __restrict__ Bsw,
    int num_ent, float* __restrict__ out) {
    int tid = threadIdx.x;
    int lane = tid & 63;
    int wid = tid >> 6;
    int base = blockIdx.x * 64 + wid * 16;
    int arow = base + (lane & 15);
    if (arow >= num_ent) arow = num_ent - 1;
    int khi = (lane >> 4) << 3;  // 0,8,16,24

    f32x4 acc[8];
    f32x4 zero = {0.f, 0.f, 0.f, 0.f};
#pragma unroll
    for (int i = 0; i < 8; ++i) acc[i] = zero;

    auto run_kt = [&](bf16x8 afrag, int fid_base) {
#pragma unroll
        for (int ct = 0; ct < 8; ++ct) {
            const unsigned short* bp = Bsw + (((size_t)fid_base * 8 + ct) << 9) + (lane << 3);
            bf16x8 bfrag = *reinterpret_cast<const bf16x8*>(bp);
            acc[ct] = __builtin_amdgcn_mfma_f32_16x16x32_bf16(afrag, bfrag, acc[ct], 0, 0, 0);
        }
    };

    // planes 0,1: T2 (interleaved bf16, A-ready)
#pragma unroll
    for (int plane = 0; plane < 2; ++plane) {
        const unsigned short* Ab = T2 + ((size_t)plane * num_ent + arow) * D;
#pragma unroll
        for (int kt = 0; kt < 4; ++kt) {
            bf16x8 afrag = *reinterpret_cast<const bf16x8*>(Ab + kt * 32 + khi);
            run_kt(afrag, plane * 4 + kt);
        }
    }
    // plane 2: packed x directly (rotation folded into Bsw plane 2)
    {
        const unsigned short* Xb = XP + (size_t)arow * D;
#pragma unroll
        for (int kt = 0; kt < 4; ++kt) {
            bf16x8 afrag = *reinterpret_cast<const bf16x8*>(Xb + kt * 32 + khi);
            run_kt(afrag, 8 + kt);
        }
    }
    // store: C/D layout col=lane&15, row=(lane>>4)*4+reg
    int rbase = base + ((lane >> 4) << 2);
    int colb = lane & 15;
#pragma unroll
    for (int ct = 0; ct < 8; ++ct) {
#pragma unroll
        for (int jj = 0; jj < 4; ++jj) {
            int g = rbase + jj;
            if (g < num_ent) out[(size_t)g * D + ct * 16 + colb] = acc[ct][jj];
        }
    }
}

extern "C" void kernel_launch(void* const* d_in, const int* in_sizes, int n_in,
                              void* d_out, int out_size, void* d_ws, size_t ws_size,
                              hipStream_t stream) {
    const float* x         = (const float*)d_in[0];
    const int*   ei        = (const int*)d_in[1];
    const int*   et        = (const int*)d_in[2];
    const float* rel_embed = (const float*)d_in[3];
    const float* w_loop    = (const float*)d_in[4];
    const float* w_in      = (const float*)d_in[5];
    const float* w_out     = (const float*)d_in[6];
    const float* w_rel     = (const float*)d_in[7];
    const float* loop_rel  = (const float*)d_in[8];
    float* out = (float*)d_out;

    int num_ent = in_sizes[0] / D;
    int E2      = in_sizes[2];
    int num_rel = in_sizes[3] / DH;
    float* out2 = out + (size_t)num_ent * D;

    int n2 = 2 * num_ent;
    char* ws = (char*)d_ws;
    unsigned* deg = (unsigned*)ws;                 // 2N
    unsigned* rp  = deg + n2;                      // 2N
    unsigned* partials = rp + n2;                  // 256
    unsigned* rnk = partials + 256;                // E2
    size_t off = (size_t)(2 * n2 + 256 + E2) * sizeof(unsigned);
    off = (off + 15) & ~(size_t)15;
    int2* csr = (int2*)(ws + off);                 // E2 int2 (8 B)
    unsigned* pt2 = (unsigned*)(csr + E2);         // (num_rel+1)*64 dwords
    unsigned short* Bsw = (unsigned short*)(pt2 + (size_t)(num_rel + 1) * DH);  // 49152
    unsigned short* T2 = Bsw + (size_t)3 * 4 * 8 * 512;  // 2N*128 bf16
    unsigned* xp = (unsigned*)(T2 + (size_t)n2 * D);     // N*64 dwords

    hipMemsetAsync(deg, 0, (size_t)n2 * sizeof(unsigned), stream);

    // fused prelude block ranges: degree | xpack | tables | wswz | relout
    int nb_deg = (E2 + 256 * DEG_EPT - 1) / (256 * DEG_EPT);
    int nb_xpk = (num_ent * 16 + 255) / 256;
    int nb_tab = ((num_rel + 1) * DH + 255) / 256;
    int nb_wsw = (3 * 4 * 8 * 512) / 256;
    int nb_rel = (num_rel * DH + 255) / 256;
    int o1 = nb_deg, o2 = o1 + nb_xpk, o3 = o2 + nb_tab, o4 = o3 + nb_wsw;
    int o5 = o4 + nb_rel;
    k_prelude<<<o5, 256, 0, stream>>>(x, ei, rel_embed, loop_rel,
                                      w_in, w_out, w_loop, w_rel,
                                      num_rel, num_ent, E2, o1, o2, o3, o4,
                                      pt2, Bsw, out2, xp, deg, rnk);

    int nb1 = (n2 + CHUNK - 1) / CHUNK;
    k_scan1<<<nb1, 256, 0, stream>>>(deg, n2, rp, partials);
    k_scan2<<<1, 256, 0, stream>>>(partials, nb1);

    k_fill<<<(E2 + 255) / 256, 256, 0, stream>>>(ei, et, E2, num_ent, deg, rp,
                                                 partials, rnk, csr);

    int nwaves = (n2 + 15) / 16;
    int gblocks = (nwaves * 64 + 255) / 256;
    k_rowgather<<<gblocks, 256, 0, stream>>>(xp, csr, rp, partials, deg,
                                             E2, n2, pt2, T2);

    int cb = (num_ent + 63) / 64;
    k_combine<<<cb, 256, 0, stream>>>(T2, (const unsigned short*)xp, Bsw, num_ent, out);
}